// Round 4
// baseline (396.908 us; speedup 1.0000x reference)
//
#include <hip/hip_runtime.h>

// IFOPooling: h_t = f_t * h_{t-1} + i_t * z_t along S (contiguous axis).
// Layout [B=16, H=1024, S=2048] fp32.
//
// Round-3 structure (512 threads, float4/thread, DPP wave scan, LDS
// cross-wave scan) kept verbatim per-row; this round changes BLOCK
// GRANULARITY only:
//   - each block processes RPB=8 consecutive rows (grid 2048, persistent-ish)
//   - register double-buffer: loads for row r+1 issue before row r's
//     scan/barrier/store -> memory pipe stays busy across row boundaries,
//     endpgm store-drain happens 2048x not 16384x
//   - LDS wa/wb double-buffered by parity -> one __syncthreads per row
//   - cross-wave serial chain: 2x ds_read_b128 + 7 predicated FMAs instead
//     of 7 dependent scalar LDS reads
//   - nontemporal stores (write-once output; protect input L3 residency)

typedef float f32x4 __attribute__((ext_vector_type(4)));

constexpr int S_LEN = 2048;
constexpr int TPB   = 512;           // 8 waves; one float4 per thread per row
constexpr int RPB   = 8;             // rows per block (even!)

// DPP ctrl encodings (gfx9/CDNA): row_shr:N = 0x110|N, row_bcast15 = 0x142,
// row_bcast31 = 0x143, wave_shr:1 = 0x138.
template<int CTRL, int RM>
__device__ __forceinline__ float dpp_mov_f(float old_v, float src) {
    return __int_as_float(__builtin_amdgcn_update_dpp(
        __float_as_int(old_v), __float_as_int(src), CTRL, RM, 0xf, false));
}

template<int CTRL, int RM>
__device__ __forceinline__ void scan_step(float& a, float& b) {
    const float a_up = dpp_mov_f<CTRL, RM>(1.0f, a);  // identity A = 1
    const float b_up = dpp_mov_f<CTRL, RM>(0.0f, b);  // identity B = 0
    b = __builtin_fmaf(a, b_up, b);   // apply current after previous
    a = a * a_up;
}

__device__ __forceinline__ void process_row(
    const float4 ff, const float4 zz, const float4 ii,
    float* __restrict__ outp, const int t, const int lane, const int wave,
    float (&wa)[2][8], float (&wb)[2][8], const int parity)
{
    float4 xx;
    xx.x = ii.x * zz.x;
    xx.y = ii.y * zz.y;
    xx.z = ii.z * zz.z;
    xx.w = ii.w * zz.w;

    // Local chunk composition: h_out = A*h_in + B
    float A = ff.x, B = xx.x;
    A = ff.y * A;  B = ff.y * B + xx.y;
    A = ff.z * A;  B = ff.z * B + xx.z;
    A = ff.w * A;  B = ff.w * B + xx.w;

    // Wave-level inclusive scan of (A,B) under composition — DPP idiom.
    float a = A, b = B;
    scan_step<0x111, 0xf>(a, b);   // row_shr:1
    scan_step<0x112, 0xf>(a, b);   // row_shr:2
    scan_step<0x114, 0xf>(a, b);   // row_shr:4
    scan_step<0x118, 0xf>(a, b);   // row_shr:8
    scan_step<0x142, 0xa>(a, b);   // row_bcast15 -> rows 1,3
    scan_step<0x143, 0xc>(a, b);   // row_bcast31 -> rows 2,3

    if (lane == 63) { wa[parity][wave] = a; wb[parity][wave] = b; }
    __syncthreads();

    // Vector-read all 8 wave ops (broadcast, conflict-free), then a
    // branchless 7-step predicated prefix — no dependent LDS chain.
    const f32x4 wa0 = *reinterpret_cast<const f32x4*>(&wa[parity][0]);
    const f32x4 wa1 = *reinterpret_cast<const f32x4*>(&wa[parity][4]);
    const f32x4 wb0 = *reinterpret_cast<const f32x4*>(&wb[parity][0]);
    const f32x4 wb1 = *reinterpret_cast<const f32x4*>(&wb[parity][4]);

    float pb = 0.0f;                 // h entering this wave's span (h_{-1}=0)
    float tmp;
    tmp = __builtin_fmaf(wa0.x, pb, wb0.x); pb = (0 < wave) ? tmp : pb;
    tmp = __builtin_fmaf(wa0.y, pb, wb0.y); pb = (1 < wave) ? tmp : pb;
    tmp = __builtin_fmaf(wa0.z, pb, wb0.z); pb = (2 < wave) ? tmp : pb;
    tmp = __builtin_fmaf(wa0.w, pb, wb0.w); pb = (3 < wave) ? tmp : pb;
    tmp = __builtin_fmaf(wa1.x, pb, wb1.x); pb = (4 < wave) ? tmp : pb;
    tmp = __builtin_fmaf(wa1.y, pb, wb1.y); pb = (5 < wave) ? tmp : pb;
    tmp = __builtin_fmaf(wa1.z, pb, wb1.z); pb = (6 < wave) ? tmp : pb;

    // Exclusive within-wave composition via wave_shr:1 (lane0 -> identity)
    const float ea = dpp_mov_f<0x138, 0xf>(1.0f, a);
    const float eb = dpp_mov_f<0x138, 0xf>(0.0f, b);

    // h entering this thread's chunk
    float h = __builtin_fmaf(ea, pb, eb);

    // Replay chunk with carried h; nontemporal store
    f32x4 oo;
    h = ff.x * h + xx.x;  oo.x = h;
    h = ff.y * h + xx.y;  oo.y = h;
    h = ff.z * h + xx.z;  oo.z = h;
    h = ff.w * h + xx.w;  oo.w = h;
    __builtin_nontemporal_store(oo, reinterpret_cast<f32x4*>(outp) + t);
}

__global__ __launch_bounds__(TPB) void ifo_scan_kernel(
    const float* __restrict__ f,
    const float* __restrict__ z,
    const float* __restrict__ iin,
    float* __restrict__ out,
    int n_rows)
{
    const int t    = threadIdx.x;
    const int lane = t & 63;
    const int wave = t >> 6;
    const size_t row0 = (size_t)blockIdx.x * RPB;
    if (row0 >= (size_t)n_rows) return;

    __shared__ __align__(16) float wa[2][8], wb[2][8];

    const float4* __restrict__ F = reinterpret_cast<const float4*>(f);
    const float4* __restrict__ Z = reinterpret_cast<const float4*>(z);
    const float4* __restrict__ I = reinterpret_cast<const float4*>(iin);
    constexpr int V4 = S_LEN / 4;    // float4s per row = 512

    const size_t v0 = row0 * V4 + t;

    // Prime the pipeline: row 0 into buffer A.
    float4 fA = F[v0], zA = Z[v0], iA = I[v0];

    #pragma unroll
    for (int r = 0; r < RPB; r += 2) {
        // Prefetch row r+1 into buffer B (issues before row r's barrier).
        const size_t i1 = v0 + (size_t)(r + 1) * V4;
        float4 fB = F[i1], zB = Z[i1], iB = I[i1];

        process_row(fA, zA, iA, out + (row0 + r) * S_LEN,
                    t, lane, wave, wa, wb, 0);

        // Prefetch row r+2 into buffer A.
        if (r + 2 < RPB) {
            const size_t i2 = v0 + (size_t)(r + 2) * V4;
            fA = F[i2]; zA = Z[i2]; iA = I[i2];
        }

        process_row(fB, zB, iB, out + (row0 + r + 1) * S_LEN,
                    t, lane, wave, wa, wb, 1);
    }
}

extern "C" void kernel_launch(void* const* d_in, const int* in_sizes, int n_in,
                              void* d_out, int out_size, void* d_ws, size_t ws_size,
                              hipStream_t stream) {
    const float* f = (const float*)d_in[0];
    const float* z = (const float*)d_in[1];
    const float* i = (const float*)d_in[2];
    float* out = (float*)d_out;

    const int rows = out_size / S_LEN;              // B*H = 16384
    const int grid = (rows + RPB - 1) / RPB;        // 2048 blocks
    ifo_scan_kernel<<<grid, TPB, 0, stream>>>(f, z, i, out, rows);
}